// Round 13
// baseline (199.666 us; speedup 1.0000x reference)
//
#include <hip/hip_runtime.h>
#include <stdint.h>

typedef _Float16 f16;
typedef __attribute__((ext_vector_type(8))) f16 f16x8;
typedef __attribute__((ext_vector_type(2))) f16 h2;
typedef __attribute__((ext_vector_type(4))) float f32x4;
typedef unsigned short u16;
typedef unsigned int u32;
typedef unsigned char u8;

#define LL 1024
#define DM 512

__device__ __forceinline__ u16 f2h(float f){ return __builtin_bit_cast(u16, (f16)f); }
__device__ __forceinline__ u32 pack2(float a, float b){
  h2 v; v.x = (f16)a; v.y = (f16)b; return __builtin_bit_cast(u32, v);
}
__device__ __forceinline__ f32x4 mfma16h(f16x8 a, f16x8 b, f32x4 c){
  return __builtin_amdgcn_mfma_f32_16x16x32_f16(a, b, c, 0, 0, 0);
}

// ---- DPP 16-lane reductions (row_ror:8/4/2/1), pure VALU, no DS ----
template<int CTRL>
__device__ __forceinline__ float dpp_mov(float x){
  return __builtin_bit_cast(float,
    __builtin_amdgcn_update_dpp(0, __builtin_bit_cast(int, x), CTRL, 0xF, 0xF, true));
}
__device__ __forceinline__ float red_add16(float v){
  v += dpp_mov<0x128>(v);
  v += dpp_mov<0x124>(v);
  v += dpp_mov<0x122>(v);
  v += dpp_mov<0x121>(v);
  return v;
}
__device__ __forceinline__ float red_max16(float v){
  v = fmaxf(v, dpp_mov<0x128>(v));
  v = fmaxf(v, dpp_mov<0x124>(v));
  v = fmaxf(v, dpp_mov<0x122>(v));
  v = fmaxf(v, dpp_mov<0x121>(v));
  return v;
}
// 32-lane group reductions: 4 DPP levels + one cross-16 swap
__device__ __forceinline__ float red_add32(float v){
  v = red_add16(v);
  v += __shfl_xor(v, 16);
  return v;
}
__device__ __forceinline__ float red_max32(float v){
  v = red_max16(v);
  v = fmaxf(v, __shfl_xor(v, 16));
  return v;
}

// ---------------- fp32 -> f16 convert ----------------
struct CvtArgs {
  const float* src[7];
  u16* dst[7];
  int n4[7];
};

__global__ __launch_bounds__(256) void cvt_kernel(CvtArgs a){
  int seg = blockIdx.y;
  const float4* s = (const float4*)a.src[seg];
  ushort4* d = (ushort4*)a.dst[seg];
  int n4 = a.n4[seg];
  for (int i = blockIdx.x*blockDim.x + threadIdx.x; i < n4; i += gridDim.x*blockDim.x){
    float4 v = s[i];
    ushort4 o;
    o.x = f2h(v.x); o.y = f2h(v.y); o.z = f2h(v.z); o.w = f2h(v.w);
    d[i] = o;
  }
}

// ---------------- fused QKV projection GEMM, 128x128 tile, BK=64 ----------------
// grid (64, 12): which = y>>2 (0=Q,1=K,2=V), nt = y&3.  f16 inputs.
// Staging via global_load_lds width=16; swizzle on GLOBAL source + LDS reads,
// LDS dest linear (rule #21).
struct QkvArgs {
  const u16* A[3];
  const u16* W[3];
  const float* bias[3];
  u16* dst[3];
  float scale[3];
};

__global__ __launch_bounds__(256,2) void proj_qkv(QkvArgs args){
  __shared__ u16 SM[128*128];          // 32 KiB: As(16K)+Bs(16K), reused as stage
  u16* As = SM;
  u16* Bs = SM + 128*64;
  const int tid = threadIdx.x;
  const int w = tid>>6, lane = tid&63;
  const int g = lane>>4, r16 = lane&15;
  const int wr = w>>1, wc = w&1;

  const int which = blockIdx.y>>2, nt = blockIdx.y&3;
  const bool isV = (which==2);
  const u16* A = args.A[which];
  const u16* W = args.W[which];
  const float* bias = args.bias[which];
  u16* dsth = args.dst[which];
  const float scale = args.scale[which];

  const int m0 = blockIdx.x*128, n0 = nt*128;

  f32x4 acc[4][4] = {};

  int rowc[4], slc[4];
  #pragma unroll
  for (int i=0;i<4;++i){
    int c = i*256+tid;
    rowc[i] = c>>3;
    slc[i] = (c&7) ^ ((c>>3)&7);
  }

  const int fswz = r16 & 7;

  for (int k0=0; k0<DM; k0+=64){
    #pragma unroll
    for (int i=0;i<4;++i){
      int c = i*256+tid;
      __builtin_amdgcn_global_load_lds(
        (const __attribute__((address_space(1))) void*)(A + (size_t)(m0+rowc[i])*DM + k0 + slc[i]*8),
        (__attribute__((address_space(3))) void*)(&As[c*8]), 16, 0, 0);
      __builtin_amdgcn_global_load_lds(
        (const __attribute__((address_space(1))) void*)(W + (size_t)(n0+rowc[i])*DM + k0 + slc[i]*8),
        (__attribute__((address_space(3))) void*)(&Bs[c*8]), 16, 0, 0);
    }
    __syncthreads();   // drains vmcnt -> staged LDS ready

    f16x8 af[4][2], bfr[4][2];
    #pragma unroll
    for (int mi=0; mi<4; ++mi){
      int row = wr*64 + mi*16 + r16;
      #pragma unroll
      for (int ks=0; ks<2; ++ks)
        af[mi][ks] = *(const f16x8*)(&As[row*64 + ((ks*4+g)^fswz)*8]);
    }
    #pragma unroll
    for (int ni=0; ni<4; ++ni){
      int row = wc*64 + ni*16 + r16;
      #pragma unroll
      for (int ks=0; ks<2; ++ks)
        bfr[ni][ks] = *(const f16x8*)(&Bs[row*64 + ((ks*4+g)^fswz)*8]);
    }
    if (isV){
      #pragma unroll
      for (int mi=0; mi<4; ++mi)
        #pragma unroll
        for (int ni=0; ni<4; ++ni){
          acc[mi][ni] = mfma16h(af[mi][0], bfr[ni][0], acc[mi][ni]);
          acc[mi][ni] = mfma16h(af[mi][1], bfr[ni][1], acc[mi][ni]);
        }
    } else {
      #pragma unroll
      for (int mi=0; mi<4; ++mi)
        #pragma unroll
        for (int ni=0; ni<4; ++ni){
          acc[mi][ni] = mfma16h(bfr[ni][0], af[mi][0], acc[mi][ni]);
          acc[mi][ni] = mfma16h(bfr[ni][1], af[mi][1], acc[mi][ni]);
        }
    }
    __syncthreads();   // all reads done before next stage overwrites
  }

  // ---- epilogue: stage into chunk-swizzled LDS, then coalesced stores
  if (!isV){
    #pragma unroll
    for (int mi=0; mi<4; ++mi){
      #pragma unroll
      for (int ni=0; ni<4; ++ni){
        f32x4 a = acc[mi][ni];
        int row = wr*64 + mi*16 + r16;
        int c   = wc*16 + ni*4 + g;
        float4 bv = *(const float4*)(bias + n0 + c*4);
        uint2 pk;
        pk.x = pack2((a[0]+bv.x)*scale, (a[1]+bv.y)*scale);
        pk.y = pack2((a[2]+bv.z)*scale, (a[3]+bv.w)*scale);
        *(uint2*)(&SM[row*128 + ((c ^ ((row&7)<<2))<<2)]) = pk;
      }
    }
  } else {
    #pragma unroll
    for (int mi=0; mi<4; ++mi){
      #pragma unroll
      for (int ni=0; ni<4; ++ni){
        f32x4 a = acc[mi][ni];
        int fl = wc*64 + ni*16 + r16;
        int kc = wr*16 + mi*4 + g;
        float bv = bias[n0 + fl];
        uint2 pk;
        pk.x = pack2(a[0]+bv, a[1]+bv);
        pk.y = pack2(a[2]+bv, a[3]+bv);
        *(uint2*)(&SM[fl*128 + ((kc ^ ((fl&7)<<2))<<2)]) = pk;
      }
    }
  }
  __syncthreads();

  #pragma unroll
  for (int rr=0; rr<8; ++rr){
    int row = w*32 + rr*4 + (lane>>4);
    int c0 = (lane&15)*2;
    int cs = c0 ^ ((row&7)<<2);
    uint4 v = *(const uint4*)(&SM[row*128 + (cs<<2)]);
    if (!isV){
      *(uint4*)(dsth + (size_t)(m0+row)*DM + n0 + (c0<<2)) = v;
    } else {
      int n = n0 + row;
      int hh = n>>6, d = n&63, bb = m0>>10;
      *(uint4*)(dsth + (size_t)((bb*8+hh)*64 + d)*1024 + (m0&1023) + (c0<<2)) = v;
    }
  }
}

// ---------------- out-projection GEMM, 64x128 tile, BK=64, grid (128,4) ----------------
__global__ __launch_bounds__(256,2) void proj_out(
    const u16* __restrict__ A, const u16* __restrict__ W,
    const float* __restrict__ bias, float* __restrict__ dstf)
{
  __shared__ u16 As[64*64];
  __shared__ u16 Bs[128*64];
  const int tid = threadIdx.x;
  const int w = tid>>6, lane = tid&63;
  const int g = lane>>4, r16 = lane&15;
  const int m0 = blockIdx.x*64, n0 = blockIdx.y*128;

  f32x4 acc[4][2] = {};

  int rowa[2], slota[2];
  #pragma unroll
  for (int i=0;i<2;++i){ int c = i*256+tid; rowa[i]=c>>3; slota[i]=c&7; }
  int rowb[4], slotb[4];
  #pragma unroll
  for (int i=0;i<4;++i){ int c = i*256+tid; rowb[i]=c>>3; slotb[i]=c&7; }

  uint4 ra[2], rb[4];
  #pragma unroll
  for (int i=0;i<2;++i)
    ra[i] = *(const uint4*)(A + (size_t)(m0+rowa[i])*DM + slota[i]*8);
  #pragma unroll
  for (int i=0;i<4;++i)
    rb[i] = *(const uint4*)(W + (size_t)(n0+rowb[i])*DM + slotb[i]*8);

  const int fswz = r16 & 7;

  for (int k0=0; k0<DM; k0+=64){
    __syncthreads();
    #pragma unroll
    for (int i=0;i<2;++i)
      *(uint4*)(&As[rowa[i]*64 + (slota[i]^(rowa[i]&7))*8]) = ra[i];
    #pragma unroll
    for (int i=0;i<4;++i)
      *(uint4*)(&Bs[rowb[i]*64 + (slotb[i]^(rowb[i]&7))*8]) = rb[i];
    __syncthreads();
    int kn = (k0+64 < DM) ? (k0+64) : 0;
    #pragma unroll
    for (int i=0;i<2;++i)
      ra[i] = *(const uint4*)(A + (size_t)(m0+rowa[i])*DM + kn + slota[i]*8);
    #pragma unroll
    for (int i=0;i<4;++i)
      rb[i] = *(const uint4*)(W + (size_t)(n0+rowb[i])*DM + kn + slotb[i]*8);

    f16x8 af[4][2], bfr[2][2];
    #pragma unroll
    for (int mi=0; mi<4; ++mi){
      int row = mi*16 + r16;
      #pragma unroll
      for (int ks=0; ks<2; ++ks)
        af[mi][ks] = *(const f16x8*)(&As[row*64 + ((ks*4+g)^fswz)*8]);
    }
    #pragma unroll
    for (int ni=0; ni<2; ++ni){
      int row = w*32 + ni*16 + r16;
      #pragma unroll
      for (int ks=0; ks<2; ++ks)
        bfr[ni][ks] = *(const f16x8*)(&Bs[row*64 + ((ks*4+g)^fswz)*8]);
    }
    #pragma unroll
    for (int mi=0; mi<4; ++mi)
      #pragma unroll
      for (int ni=0; ni<2; ++ni){
        acc[mi][ni] = mfma16h(bfr[ni][0], af[mi][0], acc[mi][ni]);
        acc[mi][ni] = mfma16h(bfr[ni][1], af[mi][1], acc[mi][ni]);
      }
  }

  #pragma unroll
  for (int mi=0; mi<4; ++mi){
    #pragma unroll
    for (int ni=0; ni<2; ++ni){
      int m  = m0 + mi*16 + r16;
      int nb = n0 + w*32 + ni*16 + g*4;
      float4 bv = *(const float4*)(bias + nb);
      float4 o;
      o.x = acc[mi][ni][0]+bv.x; o.y = acc[mi][ni][1]+bv.y;
      o.z = acc[mi][ni][2]+bv.z; o.w = acc[mi][ni][3]+bv.w;
      *(float4*)(dstf + (size_t)m*DM + nb) = o;
    }
  }
}

// ---------------- fused attention + entmax-1.5, half-tile software pipeline ----
// grid 2048, 512 threads (8 waves): bh = ((bid&7)<<3)|((bid>>3)&7), qb = bid>>6.
// 32 q-rows/block, S[32][1024] f16 (64KiB) + 2x4KiB partials -> 2 blocks/CU.
// Pipeline: A(h0) | A(h1)+B(h0) | B(h1)+C(h0) | merge(h0)+C(h1) | merge(h1).
// Mixed phases co-issue memory/MFMA and VALU work (r8-r12: phases in lockstep
// left MfmaUtil 5% + VALUBusy 45%, both pipes idle half the time, insensitive
// to occupancy/VALU-count/prefetch). Per-wave order alternates by parity.
// Swizzle: (row,k) at u16 off row*1024 + (k ^ (cc<<3)), cc = ((k>>6)&7) ^ (row&7).
__global__ __launch_bounds__(512,4) void attn_entmax(
    const u16* __restrict__ Qf, const u16* __restrict__ Kf,
    const u16* __restrict__ Vt, const u8* __restrict__ mask,
    u16* __restrict__ ctx)
{
  __shared__ u16 S[32*1024];   // 64 KiB
  __shared__ float P2a[1024];  // 4 KiB split-K partials, half 0
  __shared__ float P2b[1024];  // 4 KiB split-K partials, half 1

  const int tid = threadIdx.x, w = tid>>6, lane = tid&63;
  const int g = lane>>4, r16 = lane&15;
  const int bid = blockIdx.x;
  const int bh = ((bid&7)<<3) | ((bid>>3)&7);
  const int qb = bid>>6;
  const int b = bh>>3, h = bh&7;
  const int q0 = qb*32;
  const u16* Qb = Qf + ((size_t)(b*LL + q0))*DM + h*64;
  const u16* Kb = Kf + ((size_t)(b*LL))*DM + h*64;
  const int di = w&3, kh = w>>2;

  f16x8 qf[2][2];
  #pragma unroll
  for (int qi=0;qi<2;++qi){
    qf[qi][0] = *(const f16x8*)(Qb + (size_t)(qi*16 + r16)*DM + g*8);
    qf[qi][1] = *(const f16x8*)(Qb + (size_t)(qi*16 + r16)*DM + 32 + g*8);
  }

  // ---- A(hf): S rows [hf*16,+16) = K Q^T; wave w: keys [w*128,+128)
  auto phaseA = [&](int hf){
    #pragma unroll
    for (int kt=0; kt<8; ++kt){
      int krow = w*128 + kt*16;
      const u16* kp = Kb + (size_t)(krow + r16)*DM + g*8;
      f16x8 kf0 = *(const f16x8*)(kp);
      f16x8 kf1 = *(const f16x8*)(kp + 32);
      int kb = krow + g*4;
      u32 m4 = *(const u32*)(mask + b*LL + kb);
      f32x4 acc = {};
      acc = mfma16h(kf0, qf[hf][0], acc);   // reg-dim: key, col: q=r16
      acc = mfma16h(kf1, qf[hf][1], acc);
      float v0 = (m4 & 0xFFu)       ? -30000.f : acc[0];
      float v1 = (m4 & 0xFF00u)     ? -30000.f : acc[1];
      float v2 = (m4 & 0xFF0000u)   ? -30000.f : acc[2];
      float v3 = (m4 & 0xFF000000u) ? -30000.f : acc[3];
      int row = hf*16 + r16;
      int cc = ((kb>>6)&7) ^ (row&7);
      uint2 pk; pk.x = pack2(v0,v1); pk.y = pack2(v2,v3);
      *(uint2*)(&S[row*LL + (kb ^ (cc<<3))]) = pk;
    }
  };

  // ---- B(hf): entmax rows [hf*16,+16); 2 rows/wave, 32-lane groups,
  // 32 keys/lane as 16 h2; all-DPP+1shfl reduces; 6 Newton iters.
  auto phaseB = [&](int hf){
    const int row = hf*16 + w*2 + (lane>>5);
    const int l32 = lane&31;
    int offs[4];
    h2 zp[16];
    #pragma unroll
    for (int c=0;c<4;++c){
      int kb = l32*32 + c*8;
      int cc = ((kb>>6)&7) ^ (row&7);
      offs[c] = row*LL + (kb ^ (cc<<3));
      uint4 v = *(const uint4*)(&S[offs[c]]);
      zp[c*4+0] = __builtin_bit_cast(h2, v.x);
      zp[c*4+1] = __builtin_bit_cast(h2, v.y);
      zp[c*4+2] = __builtin_bit_cast(h2, v.z);
      zp[c*4+3] = __builtin_bit_cast(h2, v.w);
    }
    h2 m2 = zp[0];
    #pragma unroll
    for (int t=1;t<16;++t) m2 = __builtin_elementwise_max(m2, zp[t]);
    float mx = red_max32(fmaxf((float)m2.x, (float)m2.y));

    const h2 zero2 = (h2)(f16)0;
    float lo = mx - 1.0f, hi = mx, tau = mx - 0.5f;
    #pragma unroll 1
    for (int it=0; it<6; ++it){
      f16 th = (f16)tau;
      h2 t2; t2.x = th; t2.y = th;
      h2 s1a = zero2, s1b = zero2, s2a = zero2, s2b = zero2;
      #pragma unroll
      for (int t=0;t<16;t+=2){
        h2 d0 = __builtin_elementwise_max(zp[t]   - t2, zero2);
        h2 d1 = __builtin_elementwise_max(zp[t+1] - t2, zero2);
        s1a = s1a + d0;        s1b = s1b + d1;
        s2a = s2a + d0*d0;     s2b = s2b + d1*d1;
      }
      h2 s1h = s1a + s1b, s2h = s2a + s2b;
      float s1 = red_add32((float)s1h.x + (float)s1h.y);
      float s2 = red_add32((float)s2h.x + (float)s2h.y);
      if (s2 >= 1.0f) lo = tau; else hi = tau;
      float tn = tau + (s2 - 1.0f)/(2.0f*s1);
      tau = (tn >= lo && tn < hi) ? tn : 0.5f*(lo+hi);
    }
    {
      f16 th = (f16)tau;
      h2 t2; t2.x = th; t2.y = th;
      h2 psa = zero2, psb = zero2;
      #pragma unroll
      for (int t=0;t<16;t+=2){
        h2 d0 = __builtin_elementwise_max(zp[t]   - t2, zero2);
        h2 d1 = __builtin_elementwise_max(zp[t+1] - t2, zero2);
        h2 p0 = d0*d0, p1 = d1*d1;
        zp[t] = p0; zp[t+1] = p1;
        psa = psa + p0; psb = psb + p1;
      }
      h2 ps2 = psa + psb;
      float ps = red_add32((float)ps2.x + (float)ps2.y);
      f16 iv = (f16)(1.0f/ps);
      h2 i2; i2.x = iv; i2.y = iv;
      #pragma unroll
      for (int c=0;c<4;++c){
        uint4 v;
        v.x = __builtin_bit_cast(u32, (h2)(zp[c*4+0]*i2));
        v.y = __builtin_bit_cast(u32, (h2)(zp[c*4+1]*i2));
        v.z = __builtin_bit_cast(u32, (h2)(zp[c*4+2]*i2));
        v.w = __builtin_bit_cast(u32, (h2)(zp[c*4+3]*i2));
        *(uint4*)(&S[offs[c]]) = v;    // same slots this lane read
      }
    }
  };

  // ---- C(hf): rows [hf*16,+16) x 64 d; wave -> di (w&3), kh (w>>2), 16 kt.
  // kh=1 writes partials to P2x; kh=0 keeps o0/o1 in regs for merge phase.
  auto phaseC = [&](int hf, f32x4& o0, f32x4& o1, float* P2x){
    const u16* vrow = Vt + (size_t)(bh*64 + di*16 + r16)*LL;
    const int prow = hf*16 + r16;
    const int base = kh*16;
    f16x8 pc0, pc1, vc0, vc1, pn0, pn1, vn0, vn1;
    {
      int k0c = (base+0)*32 + g*8;
      int k1c = (base+1)*32 + g*8;
      int cc0 = ((k0c>>6)&7) ^ (prow&7);
      int cc1 = ((k1c>>6)&7) ^ (prow&7);
      pc0 = *(const f16x8*)(&S[prow*LL + (k0c ^ (cc0<<3))]);
      vc0 = *(const f16x8*)(vrow + k0c);
      pc1 = *(const f16x8*)(&S[prow*LL + (k1c ^ (cc1<<3))]);
      vc1 = *(const f16x8*)(vrow + k1c);
    }
    __builtin_amdgcn_s_setprio(1);
    #pragma unroll
    for (int grp=0; grp<8; ++grp){
      if (grp < 7){
        int k0n = (base+grp*2+2)*32 + g*8;
        int k1n = (base+grp*2+3)*32 + g*8;
        int cc0 = ((k0n>>6)&7) ^ (prow&7);
        int cc1 = ((k1n>>6)&7) ^ (prow&7);
        pn0 = *(const f16x8*)(&S[prow*LL + (k0n ^ (cc0<<3))]);
        vn0 = *(const f16x8*)(vrow + k0n);
        pn1 = *(const f16x8*)(&S[prow*LL + (k1n ^ (cc1<<3))]);
        vn1 = *(const f16x8*)(vrow + k1n);
      }
      o0 = mfma16h(pc0, vc0, o0);
      o1 = mfma16h(pc1, vc1, o1);
      pc0 = pn0; vc0 = vn0; pc1 = pn1; vc1 = vn1;
    }
    __builtin_amdgcn_s_setprio(0);
    if (kh == 1){
      float4 o;
      o.x = o0[0]+o1[0]; o.y = o0[1]+o1[1]; o.z = o0[2]+o1[2]; o.w = o0[3]+o1[3];
      *(float4*)(&P2x[di*256 + r16*16 + g*4]) = o;
    }
  };

  auto mergeStore = [&](int hf, f32x4 o0, f32x4 o1, const float* P2x){
    float4 p = *(const float4*)(&P2x[di*256 + r16*16 + g*4]);
    u16* cp = ctx + (size_t)(b*LL + q0 + hf*16 + g*4)*DM + h*64 + di*16 + r16;
    cp[0*DM] = f2h(o0[0]+o1[0]+p.x);
    cp[1*DM] = f2h(o0[1]+o1[1]+p.y);
    cp[2*DM] = f2h(o0[2]+o1[2]+p.z);
    cp[3*DM] = f2h(o0[3]+o1[3]+p.w);
  };

  // ================= pipeline =================
  phaseA(0);
  __syncthreads();

  if (w & 1){ phaseA(1); phaseB(0); }
  else      { phaseB(0); phaseA(1); }
  __syncthreads();

  f32x4 c0o0 = {}, c0o1 = {};
  if (w & 1){ phaseB(1); phaseC(0, c0o0, c0o1, P2a); }
  else      { phaseC(0, c0o0, c0o1, P2a); phaseB(1); }
  __syncthreads();

  f32x4 c1o0 = {}, c1o1 = {};
  if (kh == 0) mergeStore(0, c0o0, c0o1, P2a);
  phaseC(1, c1o0, c1o1, P2b);
  __syncthreads();

  if (kh == 0) mergeStore(1, c1o0, c1o1, P2b);
}

// ---------------- launch ----------------
extern "C" void kernel_launch(void* const* d_in, const int* in_sizes, int n_in,
                              void* d_out, int out_size, void* d_ws, size_t ws_size,
                              hipStream_t stream) {
  const float* query = (const float*)d_in[0];
  const float* key   = (const float*)d_in[1];
  const float* value = (const float*)d_in[2];
  const u8*    maskp = (const u8*)d_in[3];
  const float* q_w = (const float*)d_in[4];
  const float* q_b = (const float*)d_in[5];
  const float* k_w = (const float*)d_in[6];
  const float* k_b = (const float*)d_in[7];
  const float* v_w = (const float*)d_in[8];
  const float* v_b = (const float*)d_in[9];
  const float* out_w = (const float*)d_in[10];
  const float* out_b = (const float*)d_in[11];
  float* out = (float*)d_out;

  u16* qx = (u16*)d_ws;                 // 4M f16 elems each
  u16* kx = qx + 4194304;
  u16* vx = kx + 4194304;
  u16* wq = vx + 4194304;               // 256K elems each
  u16* wk = wq + 262144;
  u16* wv = wk + 262144;
  u16* wo = wv + 262144;
  u16* Qbuf = wo + 262144;              // 4M elems each
  u16* Kbuf = Qbuf + 4194304;
  u16* Vt   = Kbuf + 4194304;
  u16* ctxb = Vt + 4194304;

  CvtArgs ca;
  ca.src[0]=query; ca.dst[0]=qx; ca.n4[0]=8*LL*DM/4;
  ca.src[1]=key;   ca.dst[1]=kx; ca.n4[1]=8*LL*DM/4;
  ca.src[2]=value; ca.dst[2]=vx; ca.n4[2]=8*LL*DM/4;
  ca.src[3]=q_w;   ca.dst[3]=wq; ca.n4[3]=DM*DM/4;
  ca.src[4]=k_w;   ca.dst[4]=wk; ca.n4[4]=DM*DM/4;
  ca.src[5]=v_w;   ca.dst[5]=wv; ca.n4[5]=DM*DM/4;
  ca.src[6]=out_w; ca.dst[6]=wo; ca.n4[6]=DM*DM/4;
  cvt_kernel<<<dim3(512,7),256,0,stream>>>(ca);

  QkvArgs qa;
  qa.A[0]=qx; qa.A[1]=kx; qa.A[2]=vx;
  qa.W[0]=wq; qa.W[1]=wk; qa.W[2]=wv;
  qa.bias[0]=q_b; qa.bias[1]=k_b; qa.bias[2]=v_b;
  qa.dst[0]=Qbuf; qa.dst[1]=Kbuf; qa.dst[2]=Vt;
  qa.scale[0]=0.0625f; qa.scale[1]=1.0f; qa.scale[2]=1.0f; // 1/8 (dh^-0.5) * 1/2 on Q

  proj_qkv<<<dim3(64,12),256,0,stream>>>(qa);

  attn_entmax<<<dim3(2048),512,0,stream>>>(Qbuf, Kbuf, Vt, maskp, ctxb);

  proj_out<<<dim3(128,4),256,0,stream>>>(ctxb, wo, out_b, out);
}

// Round 14
// 179.950 us; speedup vs baseline: 1.1096x; 1.1096x over previous
//
#include <hip/hip_runtime.h>
#include <stdint.h>

typedef _Float16 f16;
typedef __attribute__((ext_vector_type(8))) f16 f16x8;
typedef __attribute__((ext_vector_type(2))) f16 h2;
typedef __attribute__((ext_vector_type(4))) float f32x4;
typedef unsigned short u16;
typedef unsigned int u32;
typedef unsigned char u8;

#define LL 1024
#define DM 512

__device__ __forceinline__ u16 f2h(float f){ return __builtin_bit_cast(u16, (f16)f); }
__device__ __forceinline__ u32 pack2(float a, float b){
  h2 v; v.x = (f16)a; v.y = (f16)b; return __builtin_bit_cast(u32, v);
}
__device__ __forceinline__ f32x4 mfma16h(f16x8 a, f16x8 b, f32x4 c){
  return __builtin_amdgcn_mfma_f32_16x16x32_f16(a, b, c, 0, 0, 0);
}

// ---- DPP 16-lane reductions (row_ror:8/4/2/1), pure VALU, no DS ----
template<int CTRL>
__device__ __forceinline__ float dpp_mov(float x){
  return __builtin_bit_cast(float,
    __builtin_amdgcn_update_dpp(0, __builtin_bit_cast(int, x), CTRL, 0xF, 0xF, true));
}
__device__ __forceinline__ float red_add16(float v){
  v += dpp_mov<0x128>(v);
  v += dpp_mov<0x124>(v);
  v += dpp_mov<0x122>(v);
  v += dpp_mov<0x121>(v);
  return v;
}
__device__ __forceinline__ float red_max16(float v){
  v = fmaxf(v, dpp_mov<0x128>(v));
  v = fmaxf(v, dpp_mov<0x124>(v));
  v = fmaxf(v, dpp_mov<0x122>(v));
  v = fmaxf(v, dpp_mov<0x121>(v));
  return v;
}

// ---------------- fp32 -> f16 convert ----------------
struct CvtArgs {
  const float* src[7];
  u16* dst[7];
  int n4[7];
};

__global__ __launch_bounds__(256) void cvt_kernel(CvtArgs a){
  int seg = blockIdx.y;
  const float4* s = (const float4*)a.src[seg];
  ushort4* d = (ushort4*)a.dst[seg];
  int n4 = a.n4[seg];
  for (int i = blockIdx.x*blockDim.x + threadIdx.x; i < n4; i += gridDim.x*blockDim.x){
    float4 v = s[i];
    ushort4 o;
    o.x = f2h(v.x); o.y = f2h(v.y); o.z = f2h(v.z); o.w = f2h(v.w);
    d[i] = o;
  }
}

// ---------------- fused QKV projection GEMM, 128x128 tile, BK=64 ----------------
// grid (64, 12): which = y>>2 (0=Q,1=K,2=V), nt = y&3.  f16 inputs.
// Staging via global_load_lds width=16; swizzle on GLOBAL source + LDS reads,
// LDS dest linear (rule #21).
struct QkvArgs {
  const u16* A[3];
  const u16* W[3];
  const float* bias[3];
  u16* dst[3];
  float scale[3];
};

__global__ __launch_bounds__(256,2) void proj_qkv(QkvArgs args){
  __shared__ u16 SM[128*128];          // 32 KiB: As(16K)+Bs(16K), reused as stage
  u16* As = SM;
  u16* Bs = SM + 128*64;
  const int tid = threadIdx.x;
  const int w = tid>>6, lane = tid&63;
  const int g = lane>>4, r16 = lane&15;
  const int wr = w>>1, wc = w&1;

  const int which = blockIdx.y>>2, nt = blockIdx.y&3;
  const bool isV = (which==2);
  const u16* A = args.A[which];
  const u16* W = args.W[which];
  const float* bias = args.bias[which];
  u16* dsth = args.dst[which];
  const float scale = args.scale[which];

  const int m0 = blockIdx.x*128, n0 = nt*128;

  f32x4 acc[4][4] = {};

  int rowc[4], slc[4];
  #pragma unroll
  for (int i=0;i<4;++i){
    int c = i*256+tid;
    rowc[i] = c>>3;
    slc[i] = (c&7) ^ ((c>>3)&7);
  }

  const int fswz = r16 & 7;

  for (int k0=0; k0<DM; k0+=64){
    #pragma unroll
    for (int i=0;i<4;++i){
      int c = i*256+tid;
      __builtin_amdgcn_global_load_lds(
        (const __attribute__((address_space(1))) void*)(A + (size_t)(m0+rowc[i])*DM + k0 + slc[i]*8),
        (__attribute__((address_space(3))) void*)(&As[c*8]), 16, 0, 0);
      __builtin_amdgcn_global_load_lds(
        (const __attribute__((address_space(1))) void*)(W + (size_t)(n0+rowc[i])*DM + k0 + slc[i]*8),
        (__attribute__((address_space(3))) void*)(&Bs[c*8]), 16, 0, 0);
    }
    __syncthreads();   // drains vmcnt -> staged LDS ready

    f16x8 af[4][2], bfr[4][2];
    #pragma unroll
    for (int mi=0; mi<4; ++mi){
      int row = wr*64 + mi*16 + r16;
      #pragma unroll
      for (int ks=0; ks<2; ++ks)
        af[mi][ks] = *(const f16x8*)(&As[row*64 + ((ks*4+g)^fswz)*8]);
    }
    #pragma unroll
    for (int ni=0; ni<4; ++ni){
      int row = wc*64 + ni*16 + r16;
      #pragma unroll
      for (int ks=0; ks<2; ++ks)
        bfr[ni][ks] = *(const f16x8*)(&Bs[row*64 + ((ks*4+g)^fswz)*8]);
    }
    if (isV){
      #pragma unroll
      for (int mi=0; mi<4; ++mi)
        #pragma unroll
        for (int ni=0; ni<4; ++ni){
          acc[mi][ni] = mfma16h(af[mi][0], bfr[ni][0], acc[mi][ni]);
          acc[mi][ni] = mfma16h(af[mi][1], bfr[ni][1], acc[mi][ni]);
        }
    } else {
      #pragma unroll
      for (int mi=0; mi<4; ++mi)
        #pragma unroll
        for (int ni=0; ni<4; ++ni){
          acc[mi][ni] = mfma16h(bfr[ni][0], af[mi][0], acc[mi][ni]);
          acc[mi][ni] = mfma16h(bfr[ni][1], af[mi][1], acc[mi][ni]);
        }
    }
    __syncthreads();   // all reads done before next stage overwrites
  }

  // ---- epilogue: stage into chunk-swizzled LDS, then coalesced stores
  if (!isV){
    #pragma unroll
    for (int mi=0; mi<4; ++mi){
      #pragma unroll
      for (int ni=0; ni<4; ++ni){
        f32x4 a = acc[mi][ni];
        int row = wr*64 + mi*16 + r16;
        int c   = wc*16 + ni*4 + g;
        float4 bv = *(const float4*)(bias + n0 + c*4);
        uint2 pk;
        pk.x = pack2((a[0]+bv.x)*scale, (a[1]+bv.y)*scale);
        pk.y = pack2((a[2]+bv.z)*scale, (a[3]+bv.w)*scale);
        *(uint2*)(&SM[row*128 + ((c ^ ((row&7)<<2))<<2)]) = pk;
      }
    }
  } else {
    #pragma unroll
    for (int mi=0; mi<4; ++mi){
      #pragma unroll
      for (int ni=0; ni<4; ++ni){
        f32x4 a = acc[mi][ni];
        int fl = wc*64 + ni*16 + r16;
        int kc = wr*16 + mi*4 + g;
        float bv = bias[n0 + fl];
        uint2 pk;
        pk.x = pack2(a[0]+bv, a[1]+bv);
        pk.y = pack2(a[2]+bv, a[3]+bv);
        *(uint2*)(&SM[fl*128 + ((kc ^ ((fl&7)<<2))<<2)]) = pk;
      }
    }
  }
  __syncthreads();

  #pragma unroll
  for (int rr=0; rr<8; ++rr){
    int row = w*32 + rr*4 + (lane>>4);
    int c0 = (lane&15)*2;
    int cs = c0 ^ ((row&7)<<2);
    uint4 v = *(const uint4*)(&SM[row*128 + (cs<<2)]);
    if (!isV){
      *(uint4*)(dsth + (size_t)(m0+row)*DM + n0 + (c0<<2)) = v;
    } else {
      int n = n0 + row;
      int hh = n>>6, d = n&63, bb = m0>>10;
      *(uint4*)(dsth + (size_t)((bb*8+hh)*64 + d)*1024 + (m0&1023) + (c0<<2)) = v;
    }
  }
}

// ---------------- out-projection GEMM, 64x128 tile, BK=64, grid (128,4) ----------------
__global__ __launch_bounds__(256,2) void proj_out(
    const u16* __restrict__ A, const u16* __restrict__ W,
    const float* __restrict__ bias, float* __restrict__ dstf)
{
  __shared__ u16 As[64*64];
  __shared__ u16 Bs[128*64];
  const int tid = threadIdx.x;
  const int w = tid>>6, lane = tid&63;
  const int g = lane>>4, r16 = lane&15;
  const int m0 = blockIdx.x*64, n0 = blockIdx.y*128;

  f32x4 acc[4][2] = {};

  int rowa[2], slota[2];
  #pragma unroll
  for (int i=0;i<2;++i){ int c = i*256+tid; rowa[i]=c>>3; slota[i]=c&7; }
  int rowb[4], slotb[4];
  #pragma unroll
  for (int i=0;i<4;++i){ int c = i*256+tid; rowb[i]=c>>3; slotb[i]=c&7; }

  uint4 ra[2], rb[4];
  #pragma unroll
  for (int i=0;i<2;++i)
    ra[i] = *(const uint4*)(A + (size_t)(m0+rowa[i])*DM + slota[i]*8);
  #pragma unroll
  for (int i=0;i<4;++i)
    rb[i] = *(const uint4*)(W + (size_t)(n0+rowb[i])*DM + slotb[i]*8);

  const int fswz = r16 & 7;

  for (int k0=0; k0<DM; k0+=64){
    __syncthreads();
    #pragma unroll
    for (int i=0;i<2;++i)
      *(uint4*)(&As[rowa[i]*64 + (slota[i]^(rowa[i]&7))*8]) = ra[i];
    #pragma unroll
    for (int i=0;i<4;++i)
      *(uint4*)(&Bs[rowb[i]*64 + (slotb[i]^(rowb[i]&7))*8]) = rb[i];
    __syncthreads();
    int kn = (k0+64 < DM) ? (k0+64) : 0;
    #pragma unroll
    for (int i=0;i<2;++i)
      ra[i] = *(const uint4*)(A + (size_t)(m0+rowa[i])*DM + kn + slota[i]*8);
    #pragma unroll
    for (int i=0;i<4;++i)
      rb[i] = *(const uint4*)(W + (size_t)(n0+rowb[i])*DM + kn + slotb[i]*8);

    f16x8 af[4][2], bfr[2][2];
    #pragma unroll
    for (int mi=0; mi<4; ++mi){
      int row = mi*16 + r16;
      #pragma unroll
      for (int ks=0; ks<2; ++ks)
        af[mi][ks] = *(const f16x8*)(&As[row*64 + ((ks*4+g)^fswz)*8]);
    }
    #pragma unroll
    for (int ni=0; ni<2; ++ni){
      int row = w*32 + ni*16 + r16;
      #pragma unroll
      for (int ks=0; ks<2; ++ks)
        bfr[ni][ks] = *(const f16x8*)(&Bs[row*64 + ((ks*4+g)^fswz)*8]);
    }
    #pragma unroll
    for (int mi=0; mi<4; ++mi)
      #pragma unroll
      for (int ni=0; ni<2; ++ni){
        acc[mi][ni] = mfma16h(bfr[ni][0], af[mi][0], acc[mi][ni]);
        acc[mi][ni] = mfma16h(bfr[ni][1], af[mi][1], acc[mi][ni]);
      }
  }

  #pragma unroll
  for (int mi=0; mi<4; ++mi){
    #pragma unroll
    for (int ni=0; ni<2; ++ni){
      int m  = m0 + mi*16 + r16;
      int nb = n0 + w*32 + ni*16 + g*4;
      float4 bv = *(const float4*)(bias + nb);
      float4 o;
      o.x = acc[mi][ni][0]+bv.x; o.y = acc[mi][ni][1]+bv.y;
      o.z = acc[mi][ni][2]+bv.z; o.w = acc[mi][ni][3]+bv.w;
      *(float4*)(dstf + (size_t)m*DM + nb) = o;
    }
  }
}

// ---------------- fused attention + entmax-1.5 (r11 structure, best measured) ----
// grid 2048, 512 threads (8 waves): bh = ((bid&7)<<3)|((bid>>3)&7), qb = bid>>6.
// 32 q-rows/block, S[32][1024] f16 = 64 KiB (2 blocks/CU).
// Newton 5 iters + finalize (renorm absorbs residual tau; absmax was pinned at
// f16 rounding through 12->8->6 iters). s_setprio around phase-C MFMAs (T5).
// Swizzle: (row,k) at u16 off row*1024 + (k ^ (cc<<3)), cc = ((k>>6)&7) ^ (row&7).
__global__ __launch_bounds__(512,4) void attn_entmax(
    const u16* __restrict__ Qf, const u16* __restrict__ Kf,
    const u16* __restrict__ Vt, const u8* __restrict__ mask,
    u16* __restrict__ ctx)
{
  __shared__ u16 S[32*1024];   // 64 KiB

  const int tid = threadIdx.x, w = tid>>6, lane = tid&63;
  const int g = lane>>4, r16 = lane&15;
  const int bid = blockIdx.x;
  const int bh = ((bid&7)<<3) | ((bid>>3)&7);
  const int qb = bid>>6;
  const int b = bh>>3, h = bh&7;
  const int q0 = qb*32;
  const u16* Qb = Qf + ((size_t)(b*LL + q0))*DM + h*64;
  const u16* Kb = Kf + ((size_t)(b*LL))*DM + h*64;

  // ---- Phase A: S^T = K Q^T (scale folded into Q); wave w: keys [w*128,+128)
  // K pair-loads double-buffered 2 kt ahead.
  f16x8 qf[2][2];
  #pragma unroll
  for (int qi=0;qi<2;++qi){
    qf[qi][0] = *(const f16x8*)(Qb + (size_t)(qi*16 + r16)*DM + g*8);
    qf[qi][1] = *(const f16x8*)(Qb + (size_t)(qi*16 + r16)*DM + 32 + g*8);
  }
  {
    f16x8 kc[2][2], kn[2][2];
    #pragma unroll
    for (int j=0;j<2;++j){
      const u16* kp = Kb + (size_t)(w*128 + j*16 + r16)*DM + g*8;
      kc[j][0] = *(const f16x8*)(kp);
      kc[j][1] = *(const f16x8*)(kp + 32);
    }
    #pragma unroll
    for (int grp=0; grp<4; ++grp){
      #pragma unroll
      for (int j=0;j<2;++j){
        if (grp < 3){
          const u16* kp = Kb + (size_t)(w*128 + (grp*2+2+j)*16 + r16)*DM + g*8;
          kn[j][0] = *(const f16x8*)(kp);
          kn[j][1] = *(const f16x8*)(kp + 32);
        }
      }
      #pragma unroll
      for (int j=0;j<2;++j){
        int kt = grp*2 + j;
        int krow = w*128 + kt*16;
        int kb = krow + g*4;
        u32 m4 = *(const u32*)(mask + b*LL + kb);
        #pragma unroll
        for (int qi=0; qi<2; ++qi){
          f32x4 acc = {};
          acc = mfma16h(kc[j][0], qf[qi][0], acc);   // reg-dim: key, col: q=r16
          acc = mfma16h(kc[j][1], qf[qi][1], acc);
          float v0 = (m4 & 0xFFu)       ? -30000.f : acc[0];
          float v1 = (m4 & 0xFF00u)     ? -30000.f : acc[1];
          float v2 = (m4 & 0xFF0000u)   ? -30000.f : acc[2];
          float v3 = (m4 & 0xFF000000u) ? -30000.f : acc[3];
          int row = qi*16 + r16;
          int cc = ((kb>>6)&7) ^ (row&7);
          uint2 pk; pk.x = pack2(v0,v1); pk.y = pack2(v2,v3);
          *(uint2*)(&S[row*LL + (kb ^ (cc<<3))]) = pk;
        }
      }
      #pragma unroll
      for (int j=0;j<2;++j){ kc[j][0]=kn[j][0]; kc[j][1]=kn[j][1]; }
    }
  }
  __syncthreads();

  // ---- Phase B: entmax-1.5; row = w*4+g (4 rows/wave in parallel),
  // lane r16 holds 64 contiguous keys as 32 h2; all-DPP reduces; 5 Newton iters.
  {
    const int r = w*4 + g;
    const int ccb = (r16 ^ r) & 7;
    h2 zp[32];
    #pragma unroll
    for (int c=0;c<8;++c){
      uint4 v = *(const uint4*)(&S[r*LL + ((r16*64 + c*8) ^ (ccb<<3))]);
      zp[c*4+0] = __builtin_bit_cast(h2, v.x);
      zp[c*4+1] = __builtin_bit_cast(h2, v.y);
      zp[c*4+2] = __builtin_bit_cast(h2, v.z);
      zp[c*4+3] = __builtin_bit_cast(h2, v.w);
    }
    h2 m2 = zp[0];
    #pragma unroll
    for (int t=1;t<32;++t) m2 = __builtin_elementwise_max(m2, zp[t]);
    float mx = red_max16(fmaxf((float)m2.x, (float)m2.y));

    const h2 zero2 = (h2)(f16)0;
    float lo = mx - 1.0f, hi = mx, tau = mx - 0.5f;
    #pragma unroll 1
    for (int it=0; it<5; ++it){
      f16 th = (f16)tau;
      h2 t2; t2.x = th; t2.y = th;
      h2 s1a = zero2, s1b = zero2, s2a = zero2, s2b = zero2;
      #pragma unroll
      for (int t=0;t<32;t+=2){
        h2 d0 = __builtin_elementwise_max(zp[t]   - t2, zero2);
        h2 d1 = __builtin_elementwise_max(zp[t+1] - t2, zero2);
        s1a = s1a + d0;        s1b = s1b + d1;
        s2a = s2a + d0*d0;     s2b = s2b + d1*d1;
      }
      h2 s1h = s1a + s1b, s2h = s2a + s2b;
      float s1 = red_add16((float)s1h.x + (float)s1h.y);
      float s2 = red_add16((float)s2h.x + (float)s2h.y);
      if (s2 >= 1.0f) lo = tau; else hi = tau;
      float tn = tau + (s2 - 1.0f)/(2.0f*s1);
      tau = (tn >= lo && tn < hi) ? tn : 0.5f*(lo+hi);
    }

    {
      f16 th = (f16)tau;
      h2 t2; t2.x = th; t2.y = th;
      h2 psa = zero2, psb = zero2;
      #pragma unroll
      for (int t=0;t<32;t+=2){
        h2 d0 = __builtin_elementwise_max(zp[t]   - t2, zero2);
        h2 d1 = __builtin_elementwise_max(zp[t+1] - t2, zero2);
        h2 p0 = d0*d0, p1 = d1*d1;
        zp[t] = p0; zp[t+1] = p1;
        psa = psa + p0; psb = psb + p1;
      }
      h2 ps2 = psa + psb;
      float ps = red_add16((float)ps2.x + (float)ps2.y);
      f16 iv = (f16)(1.0f/ps);
      h2 i2; i2.x = iv; i2.y = iv;
      #pragma unroll
      for (int c=0;c<8;++c){
        uint4 v;
        v.x = __builtin_bit_cast(u32, (h2)(zp[c*4+0]*i2));
        v.y = __builtin_bit_cast(u32, (h2)(zp[c*4+1]*i2));
        v.z = __builtin_bit_cast(u32, (h2)(zp[c*4+2]*i2));
        v.w = __builtin_bit_cast(u32, (h2)(zp[c*4+3]*i2));
        *(uint4*)(&S[r*LL + ((r16*64 + c*8) ^ (ccb<<3))]) = v;  // same slots read
      }
    }
  }
  __syncthreads();

  // ---- Phase C: ctx = P @ V ; wave w -> q-tile (w>>2), d-tile (w&3);
  // P(LDS) + V(L2) loads double-buffered 4 kt ahead; setprio around MFMAs.
  const int qi = w>>2, di = w&3;
  const u16* vrow = Vt + (size_t)(bh*64 + di*16 + r16)*LL;
  const int prow = qi*16 + r16;
  f32x4 o0 = {}, o1 = {};
  {
    f16x8 pc[4], vc[4], pn[4], vn[4];
    #pragma unroll
    for (int j=0;j<4;++j){
      int k = j*32 + g*8;
      int cc = ((k>>6)&7) ^ (prow&7);
      pc[j] = *(const f16x8*)(&S[prow*LL + (k ^ (cc<<3))]);
      vc[j] = *(const f16x8*)(vrow + k);
    }
    #pragma unroll
    for (int grp=0; grp<8; ++grp){
      #pragma unroll
      for (int j=0;j<4;++j){
        if (grp < 7){
          int k = (grp*4+4+j)*32 + g*8;
          int cc = ((k>>6)&7) ^ (prow&7);
          pn[j] = *(const f16x8*)(&S[prow*LL + (k ^ (cc<<3))]);
          vn[j] = *(const f16x8*)(vrow + k);
        }
      }
      __builtin_amdgcn_s_setprio(1);
      #pragma unroll
      for (int j=0;j<4;++j){
        if (j & 1) o1 = mfma16h(pc[j], vc[j], o1);
        else       o0 = mfma16h(pc[j], vc[j], o0);
      }
      __builtin_amdgcn_s_setprio(0);
      #pragma unroll
      for (int j=0;j<4;++j){ pc[j]=pn[j]; vc[j]=vn[j]; }
    }
  }
  #pragma unroll
  for (int r=0;r<4;++r){
    int q = q0 + qi*16 + g*4 + r;
    ctx[(size_t)(b*LL + q)*DM + h*64 + di*16 + r16] = f2h(o0[r] + o1[r]);
  }
}

// ---------------- launch ----------------
extern "C" void kernel_launch(void* const* d_in, const int* in_sizes, int n_in,
                              void* d_out, int out_size, void* d_ws, size_t ws_size,
                              hipStream_t stream) {
  const float* query = (const float*)d_in[0];
  const float* key   = (const float*)d_in[1];
  const float* value = (const float*)d_in[2];
  const u8*    maskp = (const u8*)d_in[3];
  const float* q_w = (const float*)d_in[4];
  const float* q_b = (const float*)d_in[5];
  const float* k_w = (const float*)d_in[6];
  const float* k_b = (const float*)d_in[7];
  const float* v_w = (const float*)d_in[8];
  const float* v_b = (const float*)d_in[9];
  const float* out_w = (const float*)d_in[10];
  const float* out_b = (const float*)d_in[11];
  float* out = (float*)d_out;

  u16* qx = (u16*)d_ws;                 // 4M f16 elems each
  u16* kx = qx + 4194304;
  u16* vx = kx + 4194304;
  u16* wq = vx + 4194304;               // 256K elems each
  u16* wk = wq + 262144;
  u16* wv = wk + 262144;
  u16* wo = wv + 262144;
  u16* Qbuf = wo + 262144;              // 4M elems each
  u16* Kbuf = Qbuf + 4194304;
  u16* Vt   = Kbuf + 4194304;
  u16* ctxb = Vt + 4194304;

  CvtArgs ca;
  ca.src[0]=query; ca.dst[0]=qx; ca.n4[0]=8*LL*DM/4;
  ca.src[1]=key;   ca.dst[1]=kx; ca.n4[1]=8*LL*DM/4;
  ca.src[2]=value; ca.dst[2]=vx; ca.n4[2]=8*LL*DM/4;
  ca.src[3]=q_w;   ca.dst[3]=wq; ca.n4[3]=DM*DM/4;
  ca.src[4]=k_w;   ca.dst[4]=wk; ca.n4[4]=DM*DM/4;
  ca.src[5]=v_w;   ca.dst[5]=wv; ca.n4[5]=DM*DM/4;
  ca.src[6]=out_w; ca.dst[6]=wo; ca.n4[6]=DM*DM/4;
  cvt_kernel<<<dim3(512,7),256,0,stream>>>(ca);

  QkvArgs qa;
  qa.A[0]=qx; qa.A[1]=kx; qa.A[2]=vx;
  qa.W[0]=wq; qa.W[1]=wk; qa.W[2]=wv;
  qa.bias[0]=q_b; qa.bias[1]=k_b; qa.bias[2]=v_b;
  qa.dst[0]=Qbuf; qa.dst[1]=Kbuf; qa.dst[2]=Vt;
  qa.scale[0]=0.0625f; qa.scale[1]=1.0f; qa.scale[2]=1.0f; // 1/8 (dh^-0.5) * 1/2 on Q

  proj_qkv<<<dim3(64,12),256,0,stream>>>(qa);

  attn_entmax<<<dim3(2048),512,0,stream>>>(Qbuf, Kbuf, Vt, maskp, ctxb);

  proj_out<<<dim3(128,4),256,0,stream>>>(ctxb, wo, out_b, out);
}